// Round 1
// 408.387 us; speedup vs baseline: 1.1681x; 1.1681x over previous
//
#include <hip/hip_runtime.h>

#define EPS_BN 1e-5f

typedef __attribute__((ext_vector_type(8))) short short8;   // 8 bf16 (4 VGPR)
typedef __attribute__((ext_vector_type(4))) float floatx4;  // MFMA C/D

__device__ __forceinline__ short f2bf(float f) {            // RNE f32->bf16
    unsigned u = __float_as_uint(f);
    u += 0x7FFF + ((u >> 16) & 1);
    return (short)(u >> 16);
}

// ===========================================================================
// R4: latency attack on gather.
//  - 512-thread blocks (8 waves share one 32KB W table) -> 4 blocks/CU
//    = 32 waves/CU (100% occupancy) instead of 16 (LDS-capped 50%).
//  - chainmask[o] bit j set by scatter on collision: common path in gather
//    has NO next_arr load and NO __any chain wait; rare path unchanged.
//  - skip j when all 16 rows of the wave have empty slot (~7%).
//  - pack_W parallelized to 8 blocks.
//
// ws layout (bytes):
//   [512, 1024)   a[64], b[64] (finalize out)
//   [1024, +32K)  packedW: [j][tile][lane][8] bf16
//   then          partials: [128][nb] f32
//   then          slot: num_out*8 int (memset 0xFF)
//   then          next: n_vox int
//   then          chainmask: num_out u32 (memset 0x00)
// ===========================================================================

// Fragment-order W pack: packed[((j*4+t)*64+l)*8+i] = bf16(W[j][(l>>4)*8+i][(l&15)+16t])
__global__ void pack_W(const float* __restrict__ W, short* __restrict__ packed)
{
    const int s = blockIdx.x * 256 + threadIdx.x;   // 8 blocks x 256 = 2048
    const int j = s >> 8, t = (s >> 6) & 3, l = s & 63;
    const int k0 = (l >> 4) * 8, c = (l & 15) + 16 * t;
    short8 v;
#pragma unroll
    for (int i = 0; i < 8; ++i)
        v[i] = f2bf(W[(j * 32 + k0 + i) * 64 + c]);
    ((short8*)packed)[s] = v;
}

__global__ void scatter_slots(const int* __restrict__ out_idx,
                              const int* __restrict__ k_idx,
                              int* __restrict__ slot, int* __restrict__ next,
                              unsigned* __restrict__ chainmask, int n)
{
    int i = blockIdx.x * 256 + threadIdx.x;
    if (i < n) {
        const int o = out_idx[i];
        const int k = k_idx[i];
        int old = atomicExch(&slot[(size_t)o * 8 + k], i);
        next[i] = old;                       // always write: chain walk needs -1 terminator
        if (old >= 0) atomicOr(&chainmask[o], 1u << k);   // rare (~2%)
    }
}

// ---------------------------------------------------------------------------
// MFMA gather: block = 8 waves x 16 outputs = 128 outputs. Writes pre-BN y
// and per-block channel partial sums/sumsq.
// ---------------------------------------------------------------------------
__global__ __launch_bounds__(512, 8) void gather_mfma(
    const float* __restrict__ x, const short* __restrict__ packedW,
    const int* __restrict__ slot, const int* __restrict__ next_arr,
    const unsigned* __restrict__ chainmask,
    float* __restrict__ out, float* __restrict__ partials,
    int num_out, int nb)
{
    __shared__ short sW[16384];          // 32 KB: [j][tile][lane][8]
    __shared__ float s_stat[128];

    const int tid = threadIdx.x;
    if (tid < 128) s_stat[tid] = 0.f;
    for (int i = tid; i < 2048; i += 512)
        ((short8*)sW)[i] = ((const short8*)packedW)[i];
    __syncthreads();

    const int wave = tid >> 6, lane = tid & 63;
    const int quad = lane >> 4, row = lane & 15;
    const int obase = blockIdx.x * 128 + wave * 16;
    const int o = obase + row;
    const bool valid_o = (o < num_out);

    // 8 slots + chainmask for this output row
    int4 sl0 = make_int4(-1, -1, -1, -1), sl1 = sl0;
    unsigned cm = 0u;
    if (valid_o) {
        const int4* sp = (const int4*)(slot + (size_t)o * 8);
        sl0 = sp[0]; sl1 = sp[1];
        cm = chainmask[o];
    }

    floatx4 acc[4] = {{0,0,0,0},{0,0,0,0},{0,0,0,0},{0,0,0,0}};
    const short8* bw = (const short8*)sW;

#pragma unroll
    for (int j = 0; j < 8; ++j) {
        const int v = (j < 4) ? ((j == 0) ? sl0.x : (j == 1) ? sl0.y : (j == 2) ? sl0.z : sl0.w)
                              : ((j == 4) ? sl1.x : (j == 5) ? sl1.y : (j == 6) ? sl1.z : sl1.w);
        if (!__any(v >= 0)) continue;            // whole wave empty at this j
        float4 xa = make_float4(0.f, 0.f, 0.f, 0.f), xb = xa;
        if (v >= 0) {
            const float4* xp = (const float4*)(x + (size_t)v * 32) + quad * 2;
            xa = xp[0]; xb = xp[1];
        }
        if (__any((cm >> j) & 1u)) {             // rare duplicate-coord chain
            int w = (v >= 0 && ((cm >> j) & 1u)) ? next_arr[v] : -1;
            while (__any(w >= 0)) {
                if (w >= 0) {
                    const float4* xp2 = (const float4*)(x + (size_t)w * 32) + quad * 2;
                    float4 ya = xp2[0], yb = xp2[1];
                    xa.x += ya.x; xa.y += ya.y; xa.z += ya.z; xa.w += ya.w;
                    xb.x += yb.x; xb.y += yb.y; xb.z += yb.z; xb.w += yb.w;
                    w = next_arr[w];
                }
            }
        }
        short8 afrag;
        afrag[0] = f2bf(xa.x); afrag[1] = f2bf(xa.y);
        afrag[2] = f2bf(xa.z); afrag[3] = f2bf(xa.w);
        afrag[4] = f2bf(xb.x); afrag[5] = f2bf(xb.y);
        afrag[6] = f2bf(xb.z); afrag[7] = f2bf(xb.w);

        const int jb = j * 256;
#pragma unroll
        for (int t = 0; t < 4; ++t) {
            const short8 bfrag = bw[jb + t * 64 + lane];
            acc[t] = __builtin_amdgcn_mfma_f32_16x16x32_bf16(afrag, bfrag, acc[t], 0, 0, 0);
        }
    }

    // Epilogue: C layout col=lane&15, row=quad*4+reg. Store + fused stats.
#pragma unroll
    for (int t = 0; t < 4; ++t) {
        const int c = (lane & 15) + 16 * t;
        float sum = 0.f, sq = 0.f;
#pragma unroll
        for (int r = 0; r < 4; ++r) {
            const int oc = obase + quad * 4 + r;
            const float val = acc[t][r];
            if (oc < num_out) {
                out[(size_t)oc * 64 + c] = val;
                sum += val; sq += val * val;
            }
        }
        sum += __shfl_xor(sum, 16, 64); sum += __shfl_xor(sum, 32, 64);
        sq  += __shfl_xor(sq, 16, 64);  sq  += __shfl_xor(sq, 32, 64);
        if (quad == 0) {
            atomicAdd(&s_stat[c], sum);
            atomicAdd(&s_stat[64 + c], sq);
        }
    }
    __syncthreads();
    if (tid < 128) partials[(size_t)tid * nb + blockIdx.x] = s_stat[tid];
}

// One block per channel c: reduce partials, emit a[c], b[c].
// (conv bias cancels under BN: final = (acc-mean)*rsqrt(var)*gamma+beta)
__global__ __launch_bounds__(256) void reduce_finalize(
    const float* __restrict__ partials, const float* __restrict__ gamma,
    const float* __restrict__ beta, float* __restrict__ ws_ab,
    int nb, float inv_n)
{
    __shared__ float r1[256], r2[256];
    const int c = blockIdx.x, t = threadIdx.x;
    float s1 = 0.f, s2 = 0.f;
    for (int i = t; i < nb; i += 256) {
        s1 += partials[(size_t)c * nb + i];
        s2 += partials[(size_t)(c + 64) * nb + i];
    }
    r1[t] = s1; r2[t] = s2;
    __syncthreads();
    for (int d = 128; d > 0; d >>= 1) {
        if (t < d) { r1[t] += r1[t + d]; r2[t] += r2[t + d]; }
        __syncthreads();
    }
    if (t == 0) {
        const float mean = r1[0] * inv_n;
        const float var = r2[0] * inv_n - mean * mean;
        const float a = gamma[c] * rsqrtf(var + EPS_BN);
        ws_ab[c] = a;                        // a[64]
        ws_ab[64 + c] = beta[c] - mean * a;  // b[64]
    }
}

__global__ __launch_bounds__(256) void apply_kernel(
    float* __restrict__ out, const float* __restrict__ ws_ab, int n4)
{
    const int tid = blockIdx.x * 256 + threadIdx.x;
    const int stride = gridDim.x * 256;          // multiple of 16 -> cg fixed
    const int cg = tid & 15;
    const float4 a = ((const float4*)ws_ab)[cg];
    const float4 b = ((const float4*)(ws_ab + 64))[cg];
    float4* o4 = (float4*)out;
    for (int i = tid; i < n4; i += stride) {
        float4 v = o4[i];
        v.x = fmaxf(fmaf(v.x, a.x, b.x), 0.f);
        v.y = fmaxf(fmaf(v.y, a.y, b.y), 0.f);
        v.z = fmaxf(fmaf(v.z, a.z, b.z), 0.f);
        v.w = fmaxf(fmaf(v.w, a.w, b.w), 0.f);
        o4[i] = v;
    }
}

extern "C" void kernel_launch(void* const* d_in, const int* in_sizes, int n_in,
                              void* d_out, int out_size, void* d_ws, size_t ws_size,
                              hipStream_t stream)
{
    const float* x     = (const float*)d_in[0];
    const float* W     = (const float*)d_in[1];
    // d_in[2] = bias: cancels under BN, unused.
    const float* gamma = (const float*)d_in[3];
    const float* beta  = (const float*)d_in[4];
    const int* k_idx   = (const int*)d_in[5];
    const int* out_idx = (const int*)d_in[6];

    const int n_vox   = in_sizes[5];
    const int num_out = out_size / 64;
    const int nb      = (num_out + 127) / 128;   // gather blocks (128 outputs each)
    float* out = (float*)d_out;

    char* p = (char*)d_ws;
    float* ws_ab    = (float*)(p + 512);                 // a[64], b[64]
    short* packedW  = (short*)(p + 1024);                // 32 KB
    float* partials = (float*)(p + 1024 + 32768);        // 128*nb f32
    char*  p2       = p + 1024 + 32768 + (size_t)128 * nb * 4;
    int*   slot     = (int*)p2;                          // num_out*8
    int*   next     = slot + (size_t)num_out * 8;        // n_vox
    unsigned* chainmask = (unsigned*)(next + n_vox);     // num_out

    hipMemsetAsync(slot, 0xFF, (size_t)num_out * 8 * sizeof(int), stream);
    hipMemsetAsync(chainmask, 0, (size_t)num_out * sizeof(unsigned), stream);

    pack_W        <<<8, 256, 0, stream>>>(W, packedW);
    scatter_slots <<<(n_vox + 255) / 256, 256, 0, stream>>>(out_idx, k_idx, slot, next, chainmask, n_vox);
    gather_mfma   <<<nb, 512, 0, stream>>>(x, packedW, slot, next, chainmask, out, partials, num_out, nb);
    reduce_finalize<<<64, 256, 0, stream>>>(partials, gamma, beta, ws_ab, nb, 1.0f / (float)num_out);
    apply_kernel  <<<1024, 256, 0, stream>>>(out, ws_ab, out_size / 4);
}